// Round 5
// baseline (1230.751 us; speedup 1.0000x reference)
//
#include <hip/hip_runtime.h>
#include <math.h>

#define SEQ   1024
#define BATCH 1024
#define IN_F  57
#define H_F   128
#define OUT_F 18
#define MROWS 16     // batch rows per block
#define HSTR  136    // h_lds row stride in bf16 (272 B, 16B-aligned)
#define XSTR  72     // x_lds row stride in bf16 (144 B)

typedef __attribute__((ext_vector_type(8))) short bf8;     // MFMA A/B frag
typedef __attribute__((ext_vector_type(4))) float f32x4;   // MFMA C/D frag
typedef __attribute__((ext_vector_type(2))) unsigned u32x2;

static __device__ __forceinline__ short f2bf(float f) {    // fp32 -> bf16 RNE
    unsigned u = __builtin_bit_cast(unsigned, f);
    u = (u + 0x7FFFu + ((u >> 16) & 1u)) >> 16;
    return (short)u;
}
static __device__ __forceinline__ float bf2f(short s) {
    unsigned u = ((unsigned)(unsigned short)s) << 16;
    return __builtin_bit_cast(float, u);
}
// pack two f32 -> one u32 of 2x bf16 (lo=a, hi=b). No builtin on gfx950
// (learn_hip m240) -> inline asm, single VALU op, RNE.
static __device__ __forceinline__ unsigned pk2bf(float a, float b) {
    unsigned r;
    asm("v_cvt_pk_bf16_f32 %0, %1, %2" : "=v"(r) : "v"(a), "v"(b));
    return r;
}

// 64 blocks x 256 threads, block owns 16 batch rows for the whole sequence.
// R7-R9: step is ISSUE-bound (R6 falsified the vmcnt-drain theory: identical
// counters). Swap MFMA orientation to D[j][m] = MFMA(A=W-frags, B=h-frags):
// the same register fragments serve both roles (A/B lane layouts mirror), but
// now each lane's 4 C-regs are 4 ADJACENT j-columns of one h_lds row ->
//  - tanh outputs pack with v_cvt_pk_bf16_f32 (inline asm; __hip_bfloat162
//    bit_cast does not compile on this ROCm) and store as ONE ds_write_b64
//    per tile (was 8 scalar f2bf + 8 b16 writes)
//  - one-sided clamp (exp(-big)->0 is safe), tanh = 1 - 2*rcp(e^{2z}+1)
//  - x staging remapped to 16 lanes/row x 4 contiguous elems: cvt_pk + b64
// ~75 fewer VALU instrs + 9 fewer LDS writes per wave per step.
__global__ __launch_bounds__(256) void rnn_mfma_kernel(
    const float* __restrict__ X,     // [SEQ][BATCH][IN_F]
    const float* __restrict__ W_ih,  // [H_F][IN_F]
    const float* __restrict__ b_ih,  // [H_F]
    const float* __restrict__ W_hh,  // [H_F][H_F]
    const float* __restrict__ b_hh,  // [H_F]
    const float* __restrict__ W_ho,  // [OUT_F][H_F]
    const float* __restrict__ b_ho,  // [OUT_F]
    float* __restrict__ out)         // [BATCH][OUT_F] ++ [BATCH][H_F]
{
    const int tid  = threadIdx.x;
    const int lane = tid & 63;
    const int wv   = tid >> 6;
    const int n16  = lane & 15;
    const int quad = lane >> 4;
    const int b0   = blockIdx.x * MROWS;

    __shared__ short h_lds[2][MROWS][HSTR];
    __shared__ short x_lds[2][MROWS][XSTR];
    __shared__ float logits_lds[MROWS][OUT_F];
    __shared__ float red_lds[MROWS][2];

    const int j0 = wv * 32 + n16;
    const int j1 = j0 + 16;

    // ---- W_hh frags (bf16) in registers: lane holds W[j][k=quad*8+i].
    // Under the swapped orientation these are the A-operand (rows = j). ----
    const float* wp0 = W_hh + j0 * H_F + quad * 8;
    const float* wp1 = W_hh + j1 * H_F + quad * 8;
#define LDW8(P) ({ \
        f32x4 p_ = *(const f32x4*)(P); \
        f32x4 q_ = *(const f32x4*)((P) + 4); \
        bf8 f_; \
        f_[0]=f2bf(p_[0]); f_[1]=f2bf(p_[1]); f_[2]=f2bf(p_[2]); f_[3]=f2bf(p_[3]); \
        f_[4]=f2bf(q_[0]); f_[5]=f2bf(q_[1]); f_[6]=f2bf(q_[2]); f_[7]=f2bf(q_[3]); \
        f_; })
    bf8 wh00 = LDW8(wp0 +  0), wh01 = LDW8(wp0 + 32), wh02 = LDW8(wp0 + 64), wh03 = LDW8(wp0 + 96);
    bf8 wh10 = LDW8(wp1 +  0), wh11 = LDW8(wp1 + 32), wh12 = LDW8(wp1 + 64), wh13 = LDW8(wp1 + 96);

    // ---- W_ih frags (K 57->64 zero-pad) ----
#define LDWI(J, KS) ({ \
        bf8 f_; \
        _Pragma("unroll") \
        for (int i_ = 0; i_ < 8; ++i_) { \
            int k_ = (KS) * 32 + quad * 8 + i_; \
            f_[i_] = (k_ < IN_F) ? f2bf(W_ih[(J) * IN_F + k_]) : (short)0; \
        } f_; })
    bf8 wi00 = LDWI(j0, 0), wi01 = LDWI(j0, 1), wi10 = LDWI(j1, 0), wi11 = LDWI(j1, 1);

    // ---- bias vectors: D[j][m] rows j = wv*32 + 16*tile + 4*quad + r ----
    const int jq0 = wv * 32 + 4 * quad;
    f32x4 biasA, biasB;
    {
        f32x4 a0 = *(const f32x4*)(b_ih + jq0);
        f32x4 a1 = *(const f32x4*)(b_hh + jq0);
        biasA = a0 + a1;
        f32x4 b0v = *(const f32x4*)(b_ih + jq0 + 16);
        f32x4 b1v = *(const f32x4*)(b_hh + jq0 + 16);
        biasB = b0v + b1v;
    }

    // ---- x staging: 16 lanes per batch row, lane s handles k = 4s..4s+3 ----
    const int xs  = tid & 15;       // segment within row
    const int xm_ = tid >> 4;       // batch row 0..15
    const int xk0 = xs * 4;
    const bool xv = (xs < 14);      // vector lanes: k 0..55
    const bool x1 = (xs == 14);     // scalar lane:  k 56
    const size_t tstride = (size_t)BATCH * IN_F;
    const float* xb4 = X + (size_t)(b0 + xm_) * IN_F + xk0;
    const float* xb1 = X + (size_t)(b0 + xm_) * IN_F + 56;

#define XSTAGE(NB, V, S) do { \
        if (xv) { \
            u32x2 w_; \
            w_[0] = pk2bf((V)[0], (V)[1]); \
            w_[1] = pk2bf((V)[2], (V)[3]); \
            *(u32x2*)&x_lds[NB][xm_][xk0] = w_; \
        } else if (x1) { \
            x_lds[NB][xm_][56] = f2bf(S); \
        } } while (0)

    // ---- init: h0 = 0, zero x pads, stage x_0, prefetch x_1, x_2 ----
    for (int i = tid; i < MROWS * HSTR; i += 256) (&h_lds[0][0][0])[i] = 0;
    for (int i = tid; i < 2 * MROWS * XSTR; i += 256) (&x_lds[0][0][0])[i] = 0;
    f32x4 xq0 = {0,0,0,0}, xq1 = {0,0,0,0};
    float xq0s = 0.f, xq1s = 0.f;
    if (xv) {
        f32x4 v = *(const f32x4*)xb4;
        XSTAGE(0, v, 0.f);
        xq1 = *(const f32x4*)(xb4 + 1 * tstride);   // x_1 (written at T=0)
        xq0 = *(const f32x4*)(xb4 + 2 * tstride);   // x_2 (written at T=1)
    } else if (x1) {
        x_lds[0][xm_][56] = f2bf(*xb1);
        xq1s = xb1[1 * tstride];
        xq0s = xb1[2 * tstride];
    }
    __syncthreads();

    // Raw barrier: LDS visibility needs only lgkmcnt(0); do NOT drain vmcnt
    // (keeps x prefetch in flight; proven-safe in R6).
#define STEP_BARRIER() do { \
        asm volatile("s_waitcnt lgkmcnt(0)" ::: "memory"); \
        __builtin_amdgcn_s_barrier(); \
    } while (0)

    // tanh(z) = 1 - 2/(e^{2z}+1); one-sided clamp (z << 0 -> exp -> 0 -> -1)
#define TH(Z) ({ \
        float z_ = fminf((Z), 9.f); \
        float e_ = __expf(2.f * z_); \
        fmaf(-2.f, __builtin_amdgcn_rcpf(e_ + 1.f), 1.f); })

#define MFMA __builtin_amdgcn_mfma_f32_16x16x32_bf16
#define STEP(CB, NB, T, XS, XSS) do { \
        /* B-frags (h rows / x rows) — same addresses as before the swap */ \
        const short* hc = &h_lds[CB][0][0] + n16 * HSTR + quad * 8; \
        const short* xc = &x_lds[CB][0][0] + n16 * XSTR + quad * 8; \
        bf8 bh0 = *(const bf8*)(hc +  0); \
        bf8 bh1 = *(const bf8*)(hc + 32); \
        bf8 bh2 = *(const bf8*)(hc + 64); \
        bf8 bh3 = *(const bf8*)(hc + 96); \
        bf8 bx0 = *(const bf8*)(xc +  0); \
        bf8 bx1 = *(const bf8*)(xc + 32); \
        /* stage x_{T+1} (loaded 2 steps ago) into NB now */ \
        if ((T) + 1 < SEQ) XSTAGE(NB, XS, XSS); \
        /* issue load of x_{T+3} into the same parity slot */ \
        if ((T) + 3 < SEQ) { \
            if (xv)      XS  = *(const f32x4*)(xb4 + (size_t)((T) + 3) * tstride); \
            else if (x1) XSS = xb1[(size_t)((T) + 3) * tstride]; \
        } \
        /* 12 MFMAs, 4 chains of depth 3; A = W-frags, B = h/x-frags */ \
        f32x4 c0a = biasA, c0b = {0.f, 0.f, 0.f, 0.f}; \
        f32x4 c1a = biasB, c1b = {0.f, 0.f, 0.f, 0.f}; \
        c0a = MFMA(wh00, bh0, c0a, 0, 0, 0); \
        c1a = MFMA(wh10, bh0, c1a, 0, 0, 0); \
        c0b = MFMA(wh01, bh1, c0b, 0, 0, 0); \
        c1b = MFMA(wh11, bh1, c1b, 0, 0, 0); \
        c0a = MFMA(wh02, bh2, c0a, 0, 0, 0); \
        c1a = MFMA(wh12, bh2, c1a, 0, 0, 0); \
        c0b = MFMA(wh03, bh3, c0b, 0, 0, 0); \
        c1b = MFMA(wh13, bh3, c1b, 0, 0, 0); \
        c0a = MFMA(wi00, bx0, c0a, 0, 0, 0); \
        c1a = MFMA(wi10, bx0, c1a, 0, 0, 0); \
        c0b = MFMA(wi01, bx1, c0b, 0, 0, 0); \
        c1b = MFMA(wi11, bx1, c1b, 0, 0, 0); \
        /* D[j][m]: lane (quad,n16) holds j = jq0 + {0..3} (+16), m = n16.  */ \
        /* tanh -> cvt_pk pairs -> one b64 store per tile into row-major h. */ \
        { \
            float t0_ = TH(c0a[0] + c0b[0]); \
            float t1_ = TH(c0a[1] + c0b[1]); \
            float t2_ = TH(c0a[2] + c0b[2]); \
            float t3_ = TH(c0a[3] + c0b[3]); \
            u32x2 w_; \
            w_[0] = pk2bf(t0_, t1_); \
            w_[1] = pk2bf(t2_, t3_); \
            *(u32x2*)&h_lds[NB][n16][jq0] = w_; \
        } \
        { \
            float t0_ = TH(c1a[0] + c1b[0]); \
            float t1_ = TH(c1a[1] + c1b[1]); \
            float t2_ = TH(c1a[2] + c1b[2]); \
            float t3_ = TH(c1a[3] + c1b[3]); \
            u32x2 w_; \
            w_[0] = pk2bf(t0_, t1_); \
            w_[1] = pk2bf(t2_, t3_); \
            *(u32x2*)&h_lds[NB][n16][jq0 + 16] = w_; \
        } \
        STEP_BARRIER(); \
    } while (0)

    for (int t = 0; t < SEQ; t += 2) {
        STEP(0, 1, t,     xq1, xq1s);
        STEP(1, 0, t + 1, xq0, xq0s);
    }
#undef STEP
#undef MFMA

    // ---- final h (buf0) -> hT ----
    float* hT = out + (size_t)BATCH * OUT_F;
    #pragma unroll
    for (int r = 0; r < (MROWS * H_F) / 256; ++r) {
        int idx = tid + r * 256;
        int m = idx >> 7, k = idx & 127;
        hT[(size_t)(b0 + m) * H_F + k] = bf2f(h_lds[0][m][k]);
    }

    // ---- logits [16][18] ----
    for (int idx = tid; idx < MROWS * OUT_F; idx += 256) {
        int m = idx / OUT_F, o = idx - m * OUT_F;
        float acc = b_ho[o];
        for (int k = 0; k < H_F; ++k)
            acc = fmaf(bf2f(h_lds[0][m][k]), W_ho[o * H_F + k], acc);
        logits_lds[m][o] = acc;
    }
    __syncthreads();

    if (tid < MROWS) {
        float mx = -1e30f;
        #pragma unroll
        for (int o = 0; o < OUT_F; ++o) mx = fmaxf(mx, logits_lds[tid][o]);
        float s = 0.f;
        #pragma unroll
        for (int o = 0; o < OUT_F; ++o) s += expf(logits_lds[tid][o] - mx);
        red_lds[tid][0] = mx;
        red_lds[tid][1] = logf(s);
    }
    __syncthreads();

    for (int idx = tid; idx < MROWS * OUT_F; idx += 256) {
        int m = idx / OUT_F, o = idx - m * OUT_F;
        out[(size_t)(b0 + m) * OUT_F + o] =
            logits_lds[m][o] - red_lds[m][0] - red_lds[m][1];
    }
}

extern "C" void kernel_launch(void* const* d_in, const int* in_sizes, int n_in,
                              void* d_out, int out_size, void* d_ws, size_t ws_size,
                              hipStream_t stream) {
    const float* X    = (const float*)d_in[0];
    const float* W_ih = (const float*)d_in[1];
    const float* b_ih = (const float*)d_in[2];
    const float* W_hh = (const float*)d_in[3];
    const float* b_hh = (const float*)d_in[4];
    const float* W_ho = (const float*)d_in[5];
    const float* b_ho = (const float*)d_in[6];
    float* out = (float*)d_out;

    rnn_mfma_kernel<<<dim3(BATCH / MROWS), dim3(256), 0, stream>>>(
        X, W_ih, b_ih, W_hh, b_hh, W_ho, b_ho, out);
}